// Round 1
// baseline (631.671 us; speedup 1.0000x reference)
//
#include <hip/hip_runtime.h>
#include <cstdint>
#include <cstddef>

typedef __attribute__((ext_vector_type(8))) _Float16 half8;
typedef __attribute__((ext_vector_type(4))) float f32x4;

#define DEV static __device__ __forceinline__

DEV half8 cvt8(const float* p) {
    f32x4 a = *(const f32x4*)p;
    f32x4 b = *(const f32x4*)(p + 4);
    half8 o;
    o[0] = (_Float16)a[0]; o[1] = (_Float16)a[1];
    o[2] = (_Float16)a[2]; o[3] = (_Float16)a[3];
    o[4] = (_Float16)b[0]; o[5] = (_Float16)b[1];
    o[6] = (_Float16)b[2]; o[7] = (_Float16)b[3];
    return o;
}

// C[M,N] = (A[M,K] * B[N,K]^T + bias) * scale
// A: f32 or f16 (converted to f16 during LDS staging). B: f32 (converted).
// OUT_TRANS: writes f16 VT[b][n][t] with b=row>>11, t=row&2047 (for V proj).
template<int BM, int BN, int WR, int WC, bool A_F16, bool OUT_F16, bool OUT_TRANS>
__global__ __launch_bounds__(256, 2)
void gemm_bt(const void* __restrict__ Aptr, const float* __restrict__ Bw,
             const float* __restrict__ bias, float scale,
             void* __restrict__ Cout, int M, int N, int K)
{
    constexpr int BK = 32;
    constexpr int WM = BM / WR, WN = BN / WC;
    constexpr int MF = WM / 16, NF = WN / 16;
    constexpr int LDT = 40;  // +16B pad: keeps ds_*_b128 16B-aligned, <=2-way bank conflict
    __shared__ _Float16 As[BM][LDT];
    __shared__ _Float16 Bs[BN][LDT];

    const int tid = threadIdx.x;
    const int l = tid & 63, w = tid >> 6;
    const int wr = w / WC, wc = w % WC;
    const int lr = l & 15, lh = l >> 4;
    const int bm0 = blockIdx.y * BM, bn0 = blockIdx.x * BN;

    f32x4 acc[MF][NF] = {};

    for (int k0 = 0; k0 < K; k0 += BK) {
        __syncthreads();
        for (int c = tid; c < BM * 4; c += 256) {
            int row = c >> 2, c8 = (c & 3) << 3;
            if constexpr (A_F16) {
                const _Float16* ap = (const _Float16*)Aptr + (size_t)(bm0 + row) * K + k0 + c8;
                *(half8*)&As[row][c8] = *(const half8*)ap;
            } else {
                const float* ap = (const float*)Aptr + (size_t)(bm0 + row) * K + k0 + c8;
                *(half8*)&As[row][c8] = cvt8(ap);
            }
        }
        for (int c = tid; c < BN * 4; c += 256) {
            int row = c >> 2, c8 = (c & 3) << 3;
            const float* bp = Bw + (size_t)(bn0 + row) * K + k0 + c8;
            *(half8*)&Bs[row][c8] = cvt8(bp);
        }
        __syncthreads();

        half8 a[MF], b[NF];
#pragma unroll
        for (int m = 0; m < MF; m++)
            a[m] = *(const half8*)&As[wr * WM + m * 16 + lr][lh * 8];
#pragma unroll
        for (int n = 0; n < NF; n++)
            b[n] = *(const half8*)&Bs[wc * WN + n * 16 + lr][lh * 8];
#pragma unroll
        for (int m = 0; m < MF; m++)
#pragma unroll
            for (int n = 0; n < NF; n++)
                acc[m][n] = __builtin_amdgcn_mfma_f32_16x16x32_f16(a[m], b[n], acc[m][n], 0, 0, 0);
    }

#pragma unroll
    for (int m = 0; m < MF; m++)
#pragma unroll
        for (int n = 0; n < NF; n++) {
            int row0 = bm0 + wr * WM + m * 16 + lh * 4;
            int col = bn0 + wc * WN + n * 16 + lr;
            float bv = bias[col];
#pragma unroll
            for (int j = 0; j < 4; j++) {
                float val = (acc[m][n][j] + bv) * scale;
                int row = row0 + j;
                if constexpr (OUT_TRANS) {
                    int bi = row >> 11, t = row & 2047;
                    ((_Float16*)Cout)[(((size_t)(bi * 64 + col)) << 11) + t] = (_Float16)val;
                } else if constexpr (OUT_F16) {
                    ((_Float16*)Cout)[(size_t)row * N + col] = (_Float16)val;
                } else {
                    ((float*)Cout)[(size_t)row * N + col] = val;
                }
            }
        }
}

// Fused attention. Q pre-scaled by 0.125*log2(e) -> softmax in exp2 domain.
// Grid: 256 blocks; b = blk&3 (clusters one batch's K per XCD L2), q-tile = blk>>2 (32 rows).
// Block: 8 waves; wave w owns heads 2w, 2w+1.
// Phase 1: per-lane online softmax stats (max in exp2-domain, sum), butterfly merge at end.
// Phase 2: recompute scores, p = exp2(s-m)/sum; head-sum -> LDS -> deterministic tree
// reduce -> attn_mean; P through wave-private LDS -> PV MFMA -> O (f16).
__global__ __launch_bounds__(512, 2)
void attn_kernel(const _Float16* __restrict__ Qh, const _Float16* __restrict__ Kh,
                 const _Float16* __restrict__ VT, float* __restrict__ attn_out,
                 _Float16* __restrict__ Oh)
{
    const int blk = blockIdx.x;
    const int b = blk & 3;
    const int q0 = (blk >> 2) << 5;
    const int tid = threadIdx.x;
    const int l = tid & 63, w = tid >> 6;
    const int lr = l & 15, lh = l >> 4;
    const int h0 = w << 1;

    __shared__ float pw[8][32][33];        // per-wave head-summed p partials
    __shared__ _Float16 Pld[8][32][40];    // wave-private P transpose staging

    const size_t base = (size_t)b * 2048 * 1024;
    const _Float16* Qb = Qh + base;
    const _Float16* Kb = Kh + base;

    // Q fragments: [head][mfrag][dk]  (A-layout: row=lr, k=lh*8..+8)
    half8 qf[2][2][2];
#pragma unroll
    for (int hh = 0; hh < 2; hh++)
#pragma unroll
        for (int m = 0; m < 2; m++)
#pragma unroll
            for (int dk = 0; dk < 2; dk++)
                qf[hh][m][dk] = *(const half8*)(Qb + (size_t)(q0 + m * 16 + lr) * 1024
                                                + (h0 + hh) * 64 + dk * 32 + lh * 8);

    float ml[2][2][4], sl[2][2][4];
#pragma unroll
    for (int hh = 0; hh < 2; hh++)
#pragma unroll
        for (int m = 0; m < 2; m++)
#pragma unroll
            for (int j = 0; j < 4; j++) { ml[hh][m][j] = -1e30f; sl[hh][m][j] = 0.f; }

    // ---- Phase 1: stats ----
    for (int kt = 0; kt < 64; kt++) {
        const _Float16* kp = Kb + (size_t)(kt * 32) * 1024;
#pragma unroll
        for (int hh = 0; hh < 2; hh++) {
            half8 kfh[2][2];
#pragma unroll
            for (int kfr = 0; kfr < 2; kfr++)
#pragma unroll
                for (int dk = 0; dk < 2; dk++)
                    kfh[kfr][dk] = *(const half8*)(kp + (size_t)(kfr * 16 + lr) * 1024
                                                   + (h0 + hh) * 64 + dk * 32 + lh * 8);
            f32x4 sc[2][2] = {};
#pragma unroll
            for (int m = 0; m < 2; m++)
#pragma unroll
                for (int kfr = 0; kfr < 2; kfr++)
#pragma unroll
                    for (int dk = 0; dk < 2; dk++)
                        sc[m][kfr] = __builtin_amdgcn_mfma_f32_16x16x32_f16(
                            qf[hh][m][dk], kfh[kfr][dk], sc[m][kfr], 0, 0, 0);
#pragma unroll
            for (int m = 0; m < 2; m++)
#pragma unroll
                for (int j = 0; j < 4; j++) {
                    float v0 = sc[m][0][j], v1 = sc[m][1][j];
                    float t = fmaxf(v0, v1);
                    float mo = ml[hh][m][j];
                    float mn = fmaxf(mo, t);
                    sl[hh][m][j] = sl[hh][m][j] * __builtin_amdgcn_exp2f(mo - mn)
                                 + __builtin_amdgcn_exp2f(v0 - mn)
                                 + __builtin_amdgcn_exp2f(v1 - mn);
                    ml[hh][m][j] = mn;
                }
        }
    }
    // merge stats across the 16 lanes of each column group; sl becomes 1/sum
#pragma unroll
    for (int hh = 0; hh < 2; hh++)
#pragma unroll
        for (int m = 0; m < 2; m++)
#pragma unroll
            for (int j = 0; j < 4; j++) {
                float mv = ml[hh][m][j], sv = sl[hh][m][j];
#pragma unroll
                for (int d = 1; d < 16; d <<= 1) {
                    float mo = __shfl_xor(mv, d, 64);
                    float so = __shfl_xor(sv, d, 64);
                    float mn = fmaxf(mv, mo);
                    sv = sv * __builtin_amdgcn_exp2f(mv - mn)
                       + so * __builtin_amdgcn_exp2f(mo - mn);
                    mv = mn;
                }
                ml[hh][m][j] = mv;
                sl[hh][m][j] = 1.0f / sv;
            }

    // ---- Phase 2: emit ----
    f32x4 oacc[2][2][4] = {};   // [head][mfrag][dvfrag]
    __syncthreads();

    for (int kt = 0; kt < 64; kt++) {
        const int krow = kt * 32;
        const _Float16* kp = Kb + (size_t)krow * 1024;
        half8 vf[4];  // V B-frags (shared across heads), from VT: contiguous in t
#pragma unroll
        for (int dv = 0; dv < 4; dv++)
            vf[dv] = *(const half8*)(VT + (((size_t)(b * 64 + dv * 16 + lr)) << 11) + krow + lh * 8);

        float psum[2][2][4] = {};
#pragma unroll
        for (int hh = 0; hh < 2; hh++) {
            half8 kfh[2][2];
#pragma unroll
            for (int kfr = 0; kfr < 2; kfr++)
#pragma unroll
                for (int dk = 0; dk < 2; dk++)
                    kfh[kfr][dk] = *(const half8*)(kp + (size_t)(kfr * 16 + lr) * 1024
                                                   + (h0 + hh) * 64 + dk * 32 + lh * 8);
            f32x4 sc[2][2] = {};
#pragma unroll
            for (int m = 0; m < 2; m++)
#pragma unroll
                for (int kfr = 0; kfr < 2; kfr++)
#pragma unroll
                    for (int dk = 0; dk < 2; dk++)
                        sc[m][kfr] = __builtin_amdgcn_mfma_f32_16x16x32_f16(
                            qf[hh][m][dk], kfh[kfr][dk], sc[m][kfr], 0, 0, 0);
            // p, stash transposed copy for PV A-operand
#pragma unroll
            for (int m = 0; m < 2; m++)
#pragma unroll
                for (int kfr = 0; kfr < 2; kfr++)
#pragma unroll
                    for (int j = 0; j < 4; j++) {
                        float p = __builtin_amdgcn_exp2f(sc[m][kfr][j] - ml[hh][m][j]) * sl[hh][m][j];
                        psum[m][kfr][j] += p;
                        Pld[w][m * 16 + lh * 4 + j][kfr * 16 + lr] = (_Float16)p;
                    }
            half8 pa[2];
#pragma unroll
            for (int m = 0; m < 2; m++)
                pa[m] = *(const half8*)&Pld[w][m * 16 + lr][lh * 8];
#pragma unroll
            for (int m = 0; m < 2; m++)
#pragma unroll
                for (int dv = 0; dv < 4; dv++)
                    oacc[hh][m][dv] = __builtin_amdgcn_mfma_f32_16x16x32_f16(
                        pa[m], vf[dv], oacc[hh][m][dv], 0, 0, 0);
        }
        // head-sum partials -> LDS -> deterministic reduce -> attn_mean
#pragma unroll
        for (int m = 0; m < 2; m++)
#pragma unroll
            for (int kfr = 0; kfr < 2; kfr++)
#pragma unroll
                for (int j = 0; j < 4; j++)
                    pw[w][m * 16 + lh * 4 + j][kfr * 16 + lr] = psum[m][kfr][j];
        __syncthreads();
        for (int idx = tid; idx < 1024; idx += 512) {
            int r = idx >> 5, c = idx & 31;
            float s = 0.f;
#pragma unroll
            for (int ww = 0; ww < 8; ww++) s += pw[ww][r][c];
            attn_out[(((size_t)(b * 2048 + q0 + r)) << 11) + krow + c] = s * 0.0625f;
        }
        __syncthreads();
    }

    // write O (f16) for the output projection
#pragma unroll
    for (int hh = 0; hh < 2; hh++)
#pragma unroll
        for (int m = 0; m < 2; m++)
#pragma unroll
            for (int dv = 0; dv < 4; dv++)
#pragma unroll
                for (int j = 0; j < 4; j++) {
                    int row = q0 + m * 16 + lh * 4 + j;
                    int col = (h0 + hh) * 64 + dv * 16 + lr;
                    Oh[base + (size_t)row * 1024 + col] = (_Float16)oacc[hh][m][dv][j];
                }
}

extern "C" void kernel_launch(void* const* d_in, const int* in_sizes, int n_in,
                              void* d_out, int out_size, void* d_ws, size_t ws_size,
                              hipStream_t stream)
{
    const float* q  = (const float*)d_in[0];
    const float* k  = (const float*)d_in[1];
    const float* v  = (const float*)d_in[2];
    const float* Wq = (const float*)d_in[3];
    const float* bq = (const float*)d_in[4];
    const float* Wk = (const float*)d_in[5];
    const float* bk = (const float*)d_in[6];
    const float* Wv = (const float*)d_in[7];
    const float* bv = (const float*)d_in[8];
    const float* Wo = (const float*)d_in[9];
    const float* bo = (const float*)d_in[10];

    float* y = (float*)d_out;
    float* attn_mean = y + (size_t)4 * 2048 * 1024;

    uint8_t* ws = (uint8_t*)d_ws;
    _Float16* Qh = (_Float16*)(ws);                                   // 16 MB
    _Float16* Kh = (_Float16*)(ws + (size_t)16 * 1024 * 1024);        // 16 MB
    _Float16* VT = (_Float16*)(ws + (size_t)32 * 1024 * 1024);        // 1 MB (f16 VT[b][64][2048])
    _Float16* Oh = (_Float16*)(ws + (size_t)34 * 1024 * 1024);        // 16 MB

    // fold score scale (1/8) and log2(e) into Q so softmax uses exp2 directly
    const float QS = 0.125f * 1.44269504088896340736f;

    gemm_bt<128, 128, 2, 2, false, true, false><<<dim3(8, 64), dim3(256), 0, stream>>>(
        q, Wq, bq, QS, Qh, 8192, 1024, 1024);
    gemm_bt<128, 128, 2, 2, false, true, false><<<dim3(8, 64), dim3(256), 0, stream>>>(
        k, Wk, bk, 1.0f, Kh, 8192, 1024, 1024);
    gemm_bt<128, 64, 4, 1, false, true, true><<<dim3(1, 64), dim3(256), 0, stream>>>(
        v, Wv, bv, 1.0f, VT, 8192, 64, 1024);
    attn_kernel<<<dim3(256), dim3(512), 0, stream>>>(Qh, Kh, VT, attn_mean, Oh);
    gemm_bt<128, 128, 2, 2, true, false, false><<<dim3(8, 64), dim3(256), 0, stream>>>(
        Oh, Wo, bo, 1.0f, y, 8192, 1024, 1024);
}